// Round 9
// baseline (656.385 us; speedup 1.0000x reference)
//
#include <hip/hip_runtime.h>

#define NN 20480
#define NPTS 81920   // B(4) * N(20480)
#define PS 260       // per-point plane stride (16k x 16ch + 4 pad)
#define MS 36        // mid/act row stride

__device__ __forceinline__ float redsum16(float v){
    v += __shfl_xor(v, 1); v += __shfl_xor(v, 2);
    v += __shfl_xor(v, 4); v += __shfl_xor(v, 8);
    return v;
}
__device__ __forceinline__ float redmax16(float v){
    v = fmaxf(v, __shfl_xor(v, 1)); v = fmaxf(v, __shfl_xor(v, 2));
    v = fmaxf(v, __shfl_xor(v, 4)); v = fmaxf(v, __shfl_xor(v, 8));
    return v;
}
// Wave-scope LDS producer->consumer fence (all phase dataflow is wave-local).
__device__ __forceinline__ void wsync(){
    __builtin_amdgcn_wave_barrier();
    __threadfence_block();
    __builtin_amdgcn_wave_barrier();
}

__global__ void k_fill4(float4* out, float val, int n4){
    int i = blockIdx.x * blockDim.x + threadIdx.x;
    int stride = gridDim.x * blockDim.x;
    float4 v = make_float4(val, val, val, val);
    for (; i < n4; i += stride) out[i] = v;
}

// f_pc = relu(g * (m1_W @ feature) + b), stored point-major (B,N,16) f32
__global__ __launch_bounds__(256) void k_feat0(
    const float* __restrict__ featp,
    const float* __restrict__ m1W,
    const float* __restrict__ m1g,
    const float* __restrict__ m1b,
    float* __restrict__ feat0)
{
    int p = blockIdx.x * 256 + threadIdx.x;
    if (p >= NPTS) return;
    int b = p / NN;
    int n = p - b * NN;
    float x[16];
    #pragma unroll
    for (int c = 0; c < 16; c++) x[c] = featp[(b*16 + c)*NN + n];
    float* dst = feat0 + (size_t)p * 16;
    for (int o = 0; o < 16; o++){
        float acc = 0.f;
        #pragma unroll
        for (int c = 0; c < 16; c++) acc = fmaf(m1W[o*16 + c], x[c], acc);
        dst[o] = fmaxf(fmaf(m1g[o], acc, m1b[o]), 0.f);
    }
}

// Phase B: wave = 2 points x 32 channels per pass; 2 passes cover the wave's
// 4 points. Lane owns ONE output channel o -> w[34] (loaded once) + lg[16]
// accumulators stay in registers; all F/L row reads are wave-broadcast.
__device__ __forceinline__ void phaseB(
    const float* __restrict__ fc, float* sm,
    int gOff, int dOff, int midOff, int tid)
{
    const int l  = tid & 63;
    const int o  = l & 31;
    const int h  = l >> 5;
    const int wv = tid >> 6;

    float w[34];
    {
        const float* wr = fc + o*34;
        #pragma unroll
        for (int c = 0; c < 34; c++) w[c] = wr[c];
    }

    #pragma unroll
    for (int pp = 0; pp < 2; pp++){
        const int ptB = (wv << 2) + (pp << 1) + h;
        const float* fPB = sm + ptB*PS;
        const float* lPB = sm + 2080 + ptB*PS;
        const float* fsvP = (o < 16) ? (fPB + o) : (lPB + (o - 16));

        float lg[16];
        #pragma unroll
        for (int kk = 0; kk < 16; kk++){
            float g = sm[gOff + ptB*16 + kk];
            float d = sm[dOff + ptB*16 + kk];
            float a = fmaf(w[1], d, w[0]*g);
            const float4* fr = (const float4*)(fPB + kk*16);
            const float4* lr = (const float4*)(lPB + kk*16);
            #pragma unroll
            for (int v = 0; v < 4; v++){
                float4 F = fr[v]; float4 L = lr[v];
                a = fmaf(w[2+4*v],  F.x, a); a = fmaf(w[3+4*v],  F.y, a);
                a = fmaf(w[4+4*v],  F.z, a); a = fmaf(w[5+4*v],  F.w, a);
                a = fmaf(w[18+4*v], L.x, a); a = fmaf(w[19+4*v], L.y, a);
                a = fmaf(w[20+4*v], L.z, a); a = fmaf(w[21+4*v], L.w, a);
            }
            lg[kk] = a;
        }
        float m01 = fmaxf(lg[0], lg[1]),   m23 = fmaxf(lg[2], lg[3]);
        float m45 = fmaxf(lg[4], lg[5]),   m67 = fmaxf(lg[6], lg[7]);
        float m89 = fmaxf(lg[8], lg[9]),   mab = fmaxf(lg[10], lg[11]);
        float mcd = fmaxf(lg[12], lg[13]), mef = fmaxf(lg[14], lg[15]);
        float m0 = fmaxf(fmaxf(m01, m23), fmaxf(m45, m67));
        float m1 = fmaxf(fmaxf(m89, mab), fmaxf(mcd, mef));
        float mx = fmaxf(m0, m1);
        float s = 0.f, num = 0.f;
        #pragma unroll
        for (int kk = 0; kk < 16; kk++){
            float e = __expf(lg[kk] - mx);
            s += e;
            num = fmaf(e, fsvP[kk*16], num);
        }
        sm[midOff + ptB*MS + o] = num / s;
    }
}

// ---------------- Stage 1 ----------------
// LDS floats: F=0(2080) L=2080(2080) G=4160(128) D=4288(128) MID=4416(288)
__global__ __launch_bounds__(128, 2) void k_stage1(
    const float* __restrict__ xyzp,
    const int* __restrict__ nidx,
    const float* __restrict__ feat0,
    const float* __restrict__ lm1W,
    const float* __restrict__ lm1g,
    const float* __restrict__ lm1b,
    const float* __restrict__ p1fc,
    const float* __restrict__ p1mW,
    const float* __restrict__ p1mg,
    const float* __restrict__ p1mb,
    float* __restrict__ feat1)
{
    __shared__ float sm[4704];
    const int k  = threadIdx.x & 15;
    const int pt = threadIdx.x >> 4;
    const int p  = (blockIdx.x << 3) + pt;
    const int b  = p / NN;

    // ---- Phase A ----
    {
        const int ii = nidx[(p << 4) + k];
        const int q  = b * NN + ii;
        const float4* an = (const float4*)(feat0 + (size_t)q * 16);
        const float4* as = (const float4*)(feat0 + (size_t)p * 16);
        const float sx = xyzp[p*3 + 0];
        const float sy = xyzp[p*3 + 1];
        const float sz = xyzp[p*3 + 2];
        const float nx = xyzp[q*3 + 0];
        const float ny = xyzp[q*3 + 1];
        const float nz = xyzp[q*3 + 2];

        float* fRow = sm + pt*PS + k*16;
        float sd = 0.f;
        #pragma unroll
        for (int v = 0; v < 4; v++){
            float4 A = an[v]; float4 S = as[v];
            ((float4*)fRow)[v] = A;
            sd += fabsf(S.x-A.x) + fabsf(S.y-A.y) + fabsf(S.z-A.z) + fabsf(S.w-A.w);
        }
        sm[4288 + pt*16 + k] = 2.f * __expf(-sd * 0.0625f);   // LAMDA*f_dis

        float rx = sx - nx, ry = sy - ny, rz = sz - nz;
        float r2 = rx*rx + ry*ry;
        float rdis = sqrtf(r2 + rz*rz);
        float ralpha = atan2f(ry, rx);
        float rbeta  = atan2f(rz, sqrtf(r2));
        sm[4160 + pt*16 + k] = __expf(-rdis);                 // g_dis

        float mx = redsum16(nx) * 0.0625f;
        float my = redsum16(ny) * 0.0625f;
        float mz = redsum16(nz) * 0.0625f;
        float dx = sx - mx, dy = sy - my, dz = sz - mz;
        float dalpha = atan2f(dy, dx);
        float dbeta  = atan2f(dz, sqrtf(dx*dx + dy*dy));

        const float r0 = ralpha - dalpha, r1 = rbeta - dbeta;
        float* lRow = sm + 2080 + pt*PS + k*16;
        for (int o = 0; o < 16; o++){
            const float* wr = lm1W + o*9;
            float acc =        wr[0]*r0;
            acc = fmaf(wr[1], r1,   acc); acc = fmaf(wr[2], rdis, acc);
            acc = fmaf(wr[3], sx,   acc); acc = fmaf(wr[4], sy,   acc);
            acc = fmaf(wr[5], sz,   acc); acc = fmaf(wr[6], nx,   acc);
            acc = fmaf(wr[7], ny,   acc); acc = fmaf(wr[8], nz,   acc);
            lRow[o] = fmaxf(fmaf(lm1g[o], acc, lm1b[o]), 0.f);
        }
    }
    wsync();

    phaseB(p1fc, sm, 4160, 4288, 4416, threadIdx.x);
    wsync();

    // ---- Phase C : p1m row k ----
    {
        const float4* mp = (const float4*)(sm + 4416 + pt*MS);
        const float4* w4 = (const float4*)(p1mW + k*32);
        float acc = 0.f;
        for (int i = 0; i < 8; i++){
            float4 m = mp[i]; float4 w = w4[i];
            acc = fmaf(w.x, m.x, acc); acc = fmaf(w.y, m.y, acc);
            acc = fmaf(w.z, m.z, acc); acc = fmaf(w.w, m.w, acc);
        }
        feat1[(size_t)(p << 4) + k] = fmaxf(fmaf(p1mg[k], acc, p1mb[k]), 0.f);
    }
}

// ---------------- Stage 2 ----------------
// LDS floats: F=0(2080) L=2080(2080) G=4160(128) D=4288(128) LGR=4416(8)
//             MID=4424(288) ACT=4712(288)
__global__ __launch_bounds__(128, 2) void k_stage2(
    const float* __restrict__ featp,
    const float* __restrict__ xyzp,
    const int* __restrict__ nidx,
    const float* __restrict__ feat1,
    const float* __restrict__ lm1W,
    const float* __restrict__ lm1g,
    const float* __restrict__ lm1b,
    const float* __restrict__ lm2W,
    const float* __restrict__ lm2g,
    const float* __restrict__ lm2b,
    const float* __restrict__ p2fc,
    const float* __restrict__ p2mW,
    const float* __restrict__ p2mg,
    const float* __restrict__ p2mb,
    const float* __restrict__ m2W,
    const float* __restrict__ m2g,
    const float* __restrict__ m2b,
    const float* __restrict__ scW,
    const float* __restrict__ scg,
    const float* __restrict__ scb,
    const float* __restrict__ m3W,
    const float* __restrict__ m3g,
    const float* __restrict__ m3b,
    const float* __restrict__ m4W,
    const float* __restrict__ m4g,
    const float* __restrict__ m4b,
    float* __restrict__ outp)
{
    __shared__ float sm[5000];
    const int k  = threadIdx.x & 15;
    const int pt = threadIdx.x >> 4;
    const int p  = (blockIdx.x << 3) + pt;
    const int b  = p / NN;
    const int n  = p - b * NN;

    // ---- Phase A ----
    {
        const int ii = nidx[(p << 4) + k];
        const int q  = b * NN + ii;
        const float4* an = (const float4*)(feat1 + (size_t)q * 16);
        const float4* as = (const float4*)(feat1 + (size_t)p * 16);
        const float sx = xyzp[p*3 + 0];
        const float sy = xyzp[p*3 + 1];
        const float sz = xyzp[p*3 + 2];
        const float nx = xyzp[q*3 + 0];
        const float ny = xyzp[q*3 + 1];
        const float nz = xyzp[q*3 + 2];

        float* fRow = sm + pt*PS + k*16;
        float sd = 0.f;
        #pragma unroll
        for (int v = 0; v < 4; v++){
            float4 A = an[v]; float4 S = as[v];
            ((float4*)fRow)[v] = A;
            sd += fabsf(S.x-A.x) + fabsf(S.y-A.y) + fabsf(S.z-A.z) + fabsf(S.w-A.w);
        }
        sm[4288 + pt*16 + k] = 2.f * __expf(-sd * 0.0625f);

        float rx = sx - nx, ry = sy - ny, rz = sz - nz;
        float r2 = rx*rx + ry*ry;
        float rdis = sqrtf(r2 + rz*rz);
        float ralpha = atan2f(ry, rx);
        float rbeta  = atan2f(rz, sqrtf(r2));
        sm[4160 + pt*16 + k] = __expf(-rdis);

        float mx = redsum16(nx) * 0.0625f;
        float my = redsum16(ny) * 0.0625f;
        float mz = redsum16(nz) * 0.0625f;
        float dx = sx - mx, dy = sy - my, dz = sz - mz;
        float dalpha = atan2f(dy, dx);
        float dbeta  = atan2f(dz, sqrtf(dx*dx + dy*dy));

        float mxd = redmax16(rdis);
        float nr  = sqrtf(sx*sx + sy*sy + sz*sz);
        if (k == 0) sm[4416 + pt] = (mxd*mxd*mxd) / (nr*nr*nr);   // lg_ratio

        const float r0 = ralpha - dalpha, r1 = rbeta - dbeta;
        float rep[9] = { r0, r1, rdis, sx, sy, sz, nx, ny, nz };
        float lrep[16];
        #pragma unroll
        for (int o = 0; o < 16; o++){
            float acc = 0.f;
            #pragma unroll
            for (int c = 0; c < 9; c++) acc = fmaf(lm1W[o*9 + c], rep[c], acc);
            lrep[o] = fmaxf(fmaf(lm1g[o], acc, lm1b[o]), 0.f);
        }
        float* lRow = sm + 2080 + pt*PS + k*16;
        for (int o = 0; o < 16; o++){
            float acc = 0.f;
            #pragma unroll
            for (int c = 0; c < 16; c++) acc = fmaf(lm2W[o*16 + c], lrep[c], acc);
            lRow[o] = fmaxf(fmaf(lm2g[o], acc, lm2b[o]), 0.f);   // lrep2
        }
    }
    wsync();

    phaseB(p2fc, sm, 4160, 4288, 4424, threadIdx.x);
    wsync();

    // ---- Phase C1 : p2m (relu) -> ACT ----
    {
        const float4* mp = (const float4*)(sm + 4424 + pt*MS);
        const float4* wa = (const float4*)(p2mW + k*32);
        const float4* wb = (const float4*)(p2mW + (k+16)*32);
        float actA = 0.f, actB = 0.f;
        for (int i = 0; i < 8; i++){
            float4 m = mp[i]; float4 a = wa[i]; float4 c = wb[i];
            actA = fmaf(a.x, m.x, actA); actA = fmaf(a.y, m.y, actA);
            actA = fmaf(a.z, m.z, actA); actA = fmaf(a.w, m.w, actA);
            actB = fmaf(c.x, m.x, actB); actB = fmaf(c.y, m.y, actB);
            actB = fmaf(c.z, m.z, actB); actB = fmaf(c.w, m.w, actB);
        }
        sm[4712 + pt*MS + k]      = fmaxf(fmaf(p2mg[k],    actA, p2mb[k]),    0.f);
        sm[4712 + pt*MS + k + 16] = fmaxf(fmaf(p2mg[k+16], actB, p2mb[k+16]), 0.f);
    }
    wsync();

    // ---- Phase C2 : m2 + sc + m3 -> sH (aliases pt's F slice) ----
    {
        float hA[4] = {0.f, 0.f, 0.f, 0.f};
        {
            const float4* ap = (const float4*)(sm + 4712 + pt*MS);
            for (int i = 0; i < 8; i++){
                float4 a = ap[i];
                #pragma unroll
                for (int j = 0; j < 4; j++){
                    float4 w = *(const float4*)(m2W + (k+16*j)*32 + 4*i);
                    hA[j] = fmaf(w.x, a.x, hA[j]); hA[j] = fmaf(w.y, a.y, hA[j]);
                    hA[j] = fmaf(w.z, a.z, hA[j]); hA[j] = fmaf(w.w, a.w, hA[j]);
                }
            }
        }
        float sA4[4] = {0.f, 0.f, 0.f, 0.f};
        for (int i = 0; i < 4; i++){
            float x0 = featp[(b*16 + 4*i + 0)*NN + n];
            float x1 = featp[(b*16 + 4*i + 1)*NN + n];
            float x2 = featp[(b*16 + 4*i + 2)*NN + n];
            float x3 = featp[(b*16 + 4*i + 3)*NN + n];
            #pragma unroll
            for (int j = 0; j < 4; j++){
                float4 w = *(const float4*)(scW + (k+16*j)*16 + 4*i);
                sA4[j] = fmaf(w.x, x0, sA4[j]); sA4[j] = fmaf(w.y, x1, sA4[j]);
                sA4[j] = fmaf(w.z, x2, sA4[j]); sA4[j] = fmaf(w.w, x3, sA4[j]);
            }
        }
        const float sx = xyzp[p*3 + 0];
        const float sy = xyzp[p*3 + 1];
        const float sz = xyzp[p*3 + 2];
        const float lgr = sm[4416 + pt];
        float* sH = sm + pt*PS;     // F slice of this pt (dead after phase B)
        #pragma unroll
        for (int j = 0; j < 4; j++){
            int oo = k + 16*j;
            float scv = fmaf(scg[oo], sA4[j], scb[oo]);
            float m2v = fmaf(m2g[oo], hA[j],  m2b[oo]);
            float4 w3 = *(const float4*)(m3W + oo*4);
            float acc = w3.x * sx;
            acc = fmaf(w3.y, sy,  acc);
            acc = fmaf(w3.z, sz,  acc);
            acc = fmaf(w3.w, lgr, acc);
            sH[oo]      = m2v + scv;
            sH[64 + oo] = fmaf(m3g[oo], acc, m3b[oo]);
        }
    }
    wsync();

    // ---- Phase C3 : m4 (relu) ----
    float o4[4] = {0.f, 0.f, 0.f, 0.f};
    {
        const float* hRow = sm + pt*PS;
        for (int cb = 0; cb < 32; cb++){
            const float4 hv = *(const float4*)(hRow + cb*4);
            #pragma unroll
            for (int j = 0; j < 4; j++){
                const float4 wv = *(const float4*)(m4W + (k+16*j)*128 + cb*4);
                o4[j] = fmaf(wv.x, hv.x, o4[j]);
                o4[j] = fmaf(wv.y, hv.y, o4[j]);
                o4[j] = fmaf(wv.z, hv.z, o4[j]);
                o4[j] = fmaf(wv.w, hv.w, o4[j]);
            }
        }
    }
    wsync();   // sOut aliases wave's L half (dead after phase B)
    {
        const int w   = threadIdx.x >> 6;     // wave id (0/1)
        const int l   = threadIdx.x & 63;
        float* sOutW  = sm + 2080 + w*1040;   // 256 floats used
        const int pt3 = pt & 3;
        #pragma unroll
        for (int j = 0; j < 4; j++)
            sOutW[4*(k + 16*j) + pt3] = fmaxf(fmaf(m4g[k+16*j], o4[j], m4b[k+16*j]), 0.f);
        wsync();
        const int pbase = blockIdx.x << 3;
        const int b0 = pbase / NN;
        const int n0 = pbase - b0 * NN + 4*w;
        float4 u = *(const float4*)(sOutW + 4*l);
        *(float4*)(outp + (size_t)(b0*64 + l)*NN + n0) = u;
    }
}

extern "C" void kernel_launch(void* const* d_in, const int* in_sizes, int n_in,
                              void* d_out, int out_size, void* d_ws, size_t ws_size,
                              hipStream_t stream) {
    float* outp = (float*)d_out;

    // Deterministic contract check, encoded in fill value (capture-safe).
    float fillv = 1.0f;
    bool ok = true;
    if (n_in != 32) { fillv = 5.0f; ok = false; }
    else if (in_sizes[0] != 1310720 || in_sizes[1] != 245760 ||
             in_sizes[31] != 1310720) { fillv = 7.0f; ok = false; }
    else if (out_size != 5242880) { fillv = 9.0f; ok = false; }
    else if (ws_size < (size_t)2 * NPTS * 16 * sizeof(float)) { fillv = 11.0f; ok = false; }

    k_fill4<<<1024, 256, 0, stream>>>((float4*)outp, fillv, out_size/4);
    if (!ok) return;

    const float* featp = (const float*)d_in[0];
    const float* xyzp  = (const float*)d_in[1];
    const int*   nidx  = (const int*)d_in[31];

    float* feat0 = (float*)d_ws;                       // NPTS*16 f32
    float* feat1 = (float*)d_ws + (size_t)NPTS * 16;   // NPTS*16 f32

    #define W(i) ((const float*)d_in[2 + (i)])
    k_feat0<<<NPTS/256, 256, 0, stream>>>(featp, W(0), W(1), W(2), feat0);
    k_stage1<<<NPTS/8, 128, 0, stream>>>(xyzp, nidx, feat0,
        W(3), W(4), W(5), W(9), W(10), W(11), W(12), feat1);
    k_stage2<<<NPTS/8, 128, 0, stream>>>(featp, xyzp, nidx, feat1,
        W(3), W(4), W(5),          // lm1
        W(6), W(7), W(8),          // lm2
        W(13),                     // p2fc
        W(14), W(15), W(16),       // p2m
        W(17), W(18), W(19),       // m2
        W(20), W(21), W(22),       // sc
        W(23), W(24), W(25),       // m3
        W(26), W(27), W(28),       // m4
        outp);
    #undef W
}

// Round 10
// 363.711 us; speedup vs baseline: 1.8047x; 1.8047x over previous
//
#include <hip/hip_runtime.h>

#define NN 20480
#define NPTS 81920   // B(4) * N(20480)
#define PS 260       // per-point plane stride (16k x 16ch + 4 pad)
#define MS 36        // mid/act row stride

// transposed-weight offsets inside ws weight region (floats)
#define P1FCT 0
#define P2FCT 1088
#define P1MWT 2176
#define P2MWT 2688
#define M2WT  3712
#define SCWT  5760
#define M3WT  6784
#define M4WT  7040
#define WTOT  15232

__device__ __forceinline__ float redsum16(float v){
    v += __shfl_xor(v, 1); v += __shfl_xor(v, 2);
    v += __shfl_xor(v, 4); v += __shfl_xor(v, 8);
    return v;
}
__device__ __forceinline__ float redmax16(float v){
    v = fmaxf(v, __shfl_xor(v, 1)); v = fmaxf(v, __shfl_xor(v, 2));
    v = fmaxf(v, __shfl_xor(v, 4)); v = fmaxf(v, __shfl_xor(v, 8));
    return v;
}
// Wave-scope LDS producer->consumer fence (all phase dataflow is wave-local).
__device__ __forceinline__ void wsync(){
    __builtin_amdgcn_wave_barrier();
    __threadfence_block();
    __builtin_amdgcn_wave_barrier();
}

__global__ void k_fill4(float4* out, float val, int n4){
    int i = blockIdx.x * blockDim.x + threadIdx.x;
    int stride = gridDim.x * blockDim.x;
    float4 v = make_float4(val, val, val, val);
    for (; i < n4; i += stride) out[i] = v;
}

// Transpose weight matrices to [c][o] layout so consumers read coalesced.
__global__ void k_prep(
    const float* __restrict__ p1fc, const float* __restrict__ p2fc,
    const float* __restrict__ p1mW, const float* __restrict__ p2mW,
    const float* __restrict__ m2W,  const float* __restrict__ scW,
    const float* __restrict__ m3W,  const float* __restrict__ m4W,
    float* __restrict__ wb)
{
    const float* src = p1fc; float* dst = wb; int No = 32, Nc = 34, tot = 1088;
    switch (blockIdx.x){
        case 0: break;
        case 1: src = p2fc; dst = wb + P2FCT; break;
        case 2: src = p1mW; dst = wb + P1MWT; No = 16; Nc = 32; tot = 512;  break;
        case 3: src = p2mW; dst = wb + P2MWT; No = 32; Nc = 32; tot = 1024; break;
        case 4: src = m2W;  dst = wb + M2WT;  No = 64; Nc = 32; tot = 2048; break;
        case 5: src = scW;  dst = wb + SCWT;  No = 64; Nc = 16; tot = 1024; break;
        case 6: src = m3W;  dst = wb + M3WT;  No = 64; Nc = 4;  tot = 256;  break;
        case 7: src = m4W;  dst = wb + M4WT;  No = 64; Nc = 128;tot = 8192; break;
        default: return;
    }
    for (int e = threadIdx.x; e < tot; e += 256){
        int c = e / No, o = e - c * No;
        dst[e] = src[o * Nc + c];
    }
}

// f_pc = relu(g * (m1_W @ feature) + b), stored point-major (B,N,16) f32
__global__ __launch_bounds__(256) void k_feat0(
    const float* __restrict__ featp,
    const float* __restrict__ m1W,
    const float* __restrict__ m1g,
    const float* __restrict__ m1b,
    float* __restrict__ feat0)
{
    int p = blockIdx.x * 256 + threadIdx.x;
    if (p >= NPTS) return;
    int b = p / NN;
    int n = p - b * NN;
    float x[16];
    #pragma unroll
    for (int c = 0; c < 16; c++) x[c] = featp[(b*16 + c)*NN + n];
    float* dst = feat0 + (size_t)p * 16;
    for (int o = 0; o < 16; o++){
        float acc = 0.f;
        #pragma unroll
        for (int c = 0; c < 16; c++) acc = fmaf(m1W[o*16 + c], x[c], acc);
        dst[o] = fmaxf(fmaf(m1g[o], acc, m1b[o]), 0.f);
    }
}

// Phase B: wave = 2 points x 32 channels per pass (2 passes = wave's 4 pts).
// Weight load now COALESCED from transposed fcT[c][o].
__device__ __forceinline__ void phaseB(
    const float* __restrict__ fcT, float* sm,
    int gOff, int dOff, int midOff, int tid)
{
    const int l  = tid & 63;
    const int o  = l & 31;
    const int h  = l >> 5;
    const int wv = tid >> 6;

    float w[34];
    #pragma unroll
    for (int c = 0; c < 34; c++) w[c] = fcT[c*32 + o];   // coalesced

    #pragma unroll
    for (int pp = 0; pp < 2; pp++){
        const int ptB = (wv << 2) + (pp << 1) + h;
        const float* fPB = sm + ptB*PS;
        const float* lPB = sm + 2080 + ptB*PS;
        const float* fsvP = (o < 16) ? (fPB + o) : (lPB + (o - 16));

        float lg[16];
        #pragma unroll
        for (int kk = 0; kk < 16; kk++){
            float g = sm[gOff + ptB*16 + kk];
            float d = sm[dOff + ptB*16 + kk];
            float a = fmaf(w[1], d, w[0]*g);
            const float4* fr = (const float4*)(fPB + kk*16);
            const float4* lr = (const float4*)(lPB + kk*16);
            #pragma unroll
            for (int v = 0; v < 4; v++){
                float4 F = fr[v]; float4 L = lr[v];
                a = fmaf(w[2+4*v],  F.x, a); a = fmaf(w[3+4*v],  F.y, a);
                a = fmaf(w[4+4*v],  F.z, a); a = fmaf(w[5+4*v],  F.w, a);
                a = fmaf(w[18+4*v], L.x, a); a = fmaf(w[19+4*v], L.y, a);
                a = fmaf(w[20+4*v], L.z, a); a = fmaf(w[21+4*v], L.w, a);
            }
            lg[kk] = a;
        }
        float m0 = fmaxf(fmaxf(fmaxf(lg[0],lg[1]), fmaxf(lg[2],lg[3])),
                         fmaxf(fmaxf(lg[4],lg[5]), fmaxf(lg[6],lg[7])));
        float m1 = fmaxf(fmaxf(fmaxf(lg[8],lg[9]), fmaxf(lg[10],lg[11])),
                         fmaxf(fmaxf(lg[12],lg[13]), fmaxf(lg[14],lg[15])));
        float mx = fmaxf(m0, m1);
        float s = 0.f, num = 0.f;
        #pragma unroll
        for (int kk = 0; kk < 16; kk++){
            float e = __expf(lg[kk] - mx);
            s += e;
            num = fmaf(e, fsvP[kk*16], num);
        }
        sm[midOff + ptB*MS + o] = num / s;
    }
}

// ---------------- Stage 1 ----------------
// LDS floats: F=0(2080) L=2080(2080) G=4160(128) D=4288(128) MID=4416(288)
__global__ __launch_bounds__(128, 2) void k_stage1(
    const float* __restrict__ xyzp,
    const int* __restrict__ nidx,
    const float* __restrict__ feat0,
    const float* __restrict__ lm1W,
    const float* __restrict__ lm1g,
    const float* __restrict__ lm1b,
    const float* __restrict__ wb,
    const float* __restrict__ p1mg,
    const float* __restrict__ p1mb,
    float* __restrict__ feat1)
{
    __shared__ float sm[4704];
    const int k  = threadIdx.x & 15;
    const int pt = threadIdx.x >> 4;
    const int p  = (blockIdx.x << 3) + pt;
    const int b  = p / NN;

    // ---- Phase A ----
    {
        const int ii = nidx[(p << 4) + k];
        const int q  = b * NN + ii;
        const float4* an = (const float4*)(feat0 + (size_t)q * 16);
        const float4* as = (const float4*)(feat0 + (size_t)p * 16);
        const float sx = xyzp[p*3 + 0];
        const float sy = xyzp[p*3 + 1];
        const float sz = xyzp[p*3 + 2];
        const float nx = xyzp[q*3 + 0];
        const float ny = xyzp[q*3 + 1];
        const float nz = xyzp[q*3 + 2];

        float* fRow = sm + pt*PS + k*16;
        float sd = 0.f;
        #pragma unroll
        for (int v = 0; v < 4; v++){
            float4 A = an[v]; float4 S = as[v];
            ((float4*)fRow)[v] = A;
            sd += fabsf(S.x-A.x) + fabsf(S.y-A.y) + fabsf(S.z-A.z) + fabsf(S.w-A.w);
        }
        sm[4288 + pt*16 + k] = 2.f * __expf(-sd * 0.0625f);   // LAMDA*f_dis

        float rx = sx - nx, ry = sy - ny, rz = sz - nz;
        float r2 = rx*rx + ry*ry;
        float rdis = sqrtf(r2 + rz*rz);
        float ralpha = atan2f(ry, rx);
        float rbeta  = atan2f(rz, sqrtf(r2));
        sm[4160 + pt*16 + k] = __expf(-rdis);                 // g_dis

        float mx = redsum16(nx) * 0.0625f;
        float my = redsum16(ny) * 0.0625f;
        float mz = redsum16(nz) * 0.0625f;
        float dx = sx - mx, dy = sy - my, dz = sz - mz;
        float dalpha = atan2f(dy, dx);
        float dbeta  = atan2f(dz, sqrtf(dx*dx + dy*dy));

        const float r0 = ralpha - dalpha, r1 = rbeta - dbeta;
        float* lRow = sm + 2080 + pt*PS + k*16;
        for (int o = 0; o < 16; o++){        // lm1W s_load (uniform index)
            const float* wr = lm1W + o*9;
            float acc =        wr[0]*r0;
            acc = fmaf(wr[1], r1,   acc); acc = fmaf(wr[2], rdis, acc);
            acc = fmaf(wr[3], sx,   acc); acc = fmaf(wr[4], sy,   acc);
            acc = fmaf(wr[5], sz,   acc); acc = fmaf(wr[6], nx,   acc);
            acc = fmaf(wr[7], ny,   acc); acc = fmaf(wr[8], nz,   acc);
            lRow[o] = fmaxf(fmaf(lm1g[o], acc, lm1b[o]), 0.f);
        }
    }
    wsync();

    phaseB(wb + P1FCT, sm, 4160, 4288, 4416, threadIdx.x);
    wsync();

    // ---- Phase C : p1m row k (coalesced transposed weights) ----
    {
        float mid[32];
        const float4* mp = (const float4*)(sm + 4416 + pt*MS);
        #pragma unroll
        for (int i = 0; i < 8; i++){
            float4 t = mp[i];
            mid[4*i]=t.x; mid[4*i+1]=t.y; mid[4*i+2]=t.z; mid[4*i+3]=t.w;
        }
        const float* wt = wb + P1MWT;
        float acc = 0.f;
        #pragma unroll
        for (int c = 0; c < 32; c++) acc = fmaf(wt[c*16 + k], mid[c], acc);
        feat1[(size_t)(p << 4) + k] = fmaxf(fmaf(p1mg[k], acc, p1mb[k]), 0.f);
    }
}

// ---------------- Stage 2 ----------------
// LDS floats: F=0(2080) L=2080(2080) G=4160(128) D=4288(128) LGR=4416(8)
//             MID=4424(288) ACT=4712(288) SFEAT=5000(136)
__global__ __launch_bounds__(128, 2) void k_stage2(
    const float* __restrict__ featp,
    const float* __restrict__ xyzp,
    const int* __restrict__ nidx,
    const float* __restrict__ feat1,
    const float* __restrict__ lm1W,
    const float* __restrict__ lm1g,
    const float* __restrict__ lm1b,
    const float* __restrict__ lm2W,
    const float* __restrict__ lm2g,
    const float* __restrict__ lm2b,
    const float* __restrict__ wb,
    const float* __restrict__ p2mg,
    const float* __restrict__ p2mb,
    const float* __restrict__ m2g,
    const float* __restrict__ m2b,
    const float* __restrict__ scg,
    const float* __restrict__ scb,
    const float* __restrict__ m3g,
    const float* __restrict__ m3b,
    const float* __restrict__ m4g,
    const float* __restrict__ m4b,
    float* __restrict__ outp)
{
    __shared__ float sm[5136];
    const int k  = threadIdx.x & 15;
    const int pt = threadIdx.x >> 4;
    const int p  = (blockIdx.x << 3) + pt;
    const int b  = p / NN;

    // wave-local featp staging for sc (each wave stages its own 4 points)
    {
        const int l   = threadIdx.x & 63;
        const int wv  = threadIdx.x >> 6;
        const int ch  = l >> 2;              // 0..15
        const int i4  = l & 3;               // 0..3
        const int ptS = (wv << 2) + i4;      // this wave's points
        const int pS  = (blockIdx.x << 3) + ptS;
        const int bS  = pS / NN;
        const int nS  = pS - bS * NN;
        sm[5000 + ptS*17 + ch] = featp[(bS*16 + ch)*NN + nS];
    }

    // ---- Phase A ----
    {
        const int ii = nidx[(p << 4) + k];
        const int q  = b * NN + ii;
        const float4* an = (const float4*)(feat1 + (size_t)q * 16);
        const float4* as = (const float4*)(feat1 + (size_t)p * 16);
        const float sx = xyzp[p*3 + 0];
        const float sy = xyzp[p*3 + 1];
        const float sz = xyzp[p*3 + 2];
        const float nx = xyzp[q*3 + 0];
        const float ny = xyzp[q*3 + 1];
        const float nz = xyzp[q*3 + 2];

        float* fRow = sm + pt*PS + k*16;
        float sd = 0.f;
        #pragma unroll
        for (int v = 0; v < 4; v++){
            float4 A = an[v]; float4 S = as[v];
            ((float4*)fRow)[v] = A;
            sd += fabsf(S.x-A.x) + fabsf(S.y-A.y) + fabsf(S.z-A.z) + fabsf(S.w-A.w);
        }
        sm[4288 + pt*16 + k] = 2.f * __expf(-sd * 0.0625f);

        float rx = sx - nx, ry = sy - ny, rz = sz - nz;
        float r2 = rx*rx + ry*ry;
        float rdis = sqrtf(r2 + rz*rz);
        float ralpha = atan2f(ry, rx);
        float rbeta  = atan2f(rz, sqrtf(r2));
        sm[4160 + pt*16 + k] = __expf(-rdis);

        float mx = redsum16(nx) * 0.0625f;
        float my = redsum16(ny) * 0.0625f;
        float mz = redsum16(nz) * 0.0625f;
        float dx = sx - mx, dy = sy - my, dz = sz - mz;
        float dalpha = atan2f(dy, dx);
        float dbeta  = atan2f(dz, sqrtf(dx*dx + dy*dy));

        float mxd = redmax16(rdis);
        float nr  = sqrtf(sx*sx + sy*sy + sz*sz);
        if (k == 0) sm[4416 + pt] = (mxd*mxd*mxd) / (nr*nr*nr);   // lg_ratio

        const float r0 = ralpha - dalpha, r1 = rbeta - dbeta;
        float rep[9] = { r0, r1, rdis, sx, sy, sz, nx, ny, nz };
        float lrep[16];
        #pragma unroll
        for (int o = 0; o < 16; o++){
            float acc = 0.f;
            #pragma unroll
            for (int c = 0; c < 9; c++) acc = fmaf(lm1W[o*9 + c], rep[c], acc);
            lrep[o] = fmaxf(fmaf(lm1g[o], acc, lm1b[o]), 0.f);
        }
        float* lRow = sm + 2080 + pt*PS + k*16;
        for (int o = 0; o < 16; o++){
            float acc = 0.f;
            #pragma unroll
            for (int c = 0; c < 16; c++) acc = fmaf(lm2W[o*16 + c], lrep[c], acc);
            lRow[o] = fmaxf(fmaf(lm2g[o], acc, lm2b[o]), 0.f);   // lrep2
        }
    }
    wsync();

    phaseB(wb + P2FCT, sm, 4160, 4288, 4424, threadIdx.x);
    wsync();

    // ---- Phase C1 : p2m (relu) -> ACT (coalesced transposed weights) ----
    {
        float mid[32];
        const float4* mp = (const float4*)(sm + 4424 + pt*MS);
        #pragma unroll
        for (int i = 0; i < 8; i++){
            float4 t = mp[i];
            mid[4*i]=t.x; mid[4*i+1]=t.y; mid[4*i+2]=t.z; mid[4*i+3]=t.w;
        }
        const float* wt = wb + P2MWT;
        float actA = 0.f, actB = 0.f;
        #pragma unroll
        for (int c = 0; c < 32; c++){
            actA = fmaf(wt[c*32 + k],      mid[c], actA);
            actB = fmaf(wt[c*32 + k + 16], mid[c], actB);
        }
        sm[4712 + pt*MS + k]      = fmaxf(fmaf(p2mg[k],    actA, p2mb[k]),    0.f);
        sm[4712 + pt*MS + k + 16] = fmaxf(fmaf(p2mg[k+16], actB, p2mb[k+16]), 0.f);
    }
    wsync();

    // ---- Phase C2 : m2 + sc + m3 -> sH ----
    {
        float act[32];
        const float4* ap = (const float4*)(sm + 4712 + pt*MS);
        #pragma unroll
        for (int i = 0; i < 8; i++){
            float4 t = ap[i];
            act[4*i]=t.x; act[4*i+1]=t.y; act[4*i+2]=t.z; act[4*i+3]=t.w;
        }
        const float* wt2 = wb + M2WT;
        float hA[4] = {0.f, 0.f, 0.f, 0.f};
        #pragma unroll
        for (int c = 0; c < 32; c++){
            float a = act[c];
            #pragma unroll
            for (int j = 0; j < 4; j++)
                hA[j] = fmaf(wt2[c*64 + k + 16*j], a, hA[j]);
        }
        const float* wts = wb + SCWT;
        float sA4[4] = {0.f, 0.f, 0.f, 0.f};
        #pragma unroll
        for (int c = 0; c < 16; c++){
            float x = sm[5000 + pt*17 + c];
            #pragma unroll
            for (int j = 0; j < 4; j++)
                sA4[j] = fmaf(wts[c*64 + k + 16*j], x, sA4[j]);
        }
        const float sx = xyzp[p*3 + 0];
        const float sy = xyzp[p*3 + 1];
        const float sz = xyzp[p*3 + 2];
        const float lgr = sm[4416 + pt];
        const float v3[4] = { sx, sy, sz, lgr };
        const float* wt3 = wb + M3WT;
        float* sH = sm + pt*PS;     // F slice of this pt (dead after phase B)
        #pragma unroll
        for (int j = 0; j < 4; j++){
            int oo = k + 16*j;
            float scv = fmaf(scg[oo], sA4[j], scb[oo]);
            float m2v = fmaf(m2g[oo], hA[j],  m2b[oo]);
            float acc = 0.f;
            #pragma unroll
            for (int c = 0; c < 4; c++) acc = fmaf(wt3[c*64 + oo], v3[c], acc);
            sH[oo]      = m2v + scv;
            sH[64 + oo] = fmaf(m3g[oo], acc, m3b[oo]);
        }
    }
    wsync();

    // ---- Phase C3 : m4 (relu), coalesced transposed weights ----
    float o4[4] = {0.f, 0.f, 0.f, 0.f};
    {
        const float* hRow = sm + pt*PS;
        const float* wt4 = wb + M4WT;
        for (int cb = 0; cb < 32; cb++){
            const float4 hv = *(const float4*)(hRow + cb*4);
            const float* w0 = wt4 + (cb*4)*64 + k;
            #pragma unroll
            for (int j = 0; j < 4; j++){
                o4[j] = fmaf(w0[16*j],       hv.x, o4[j]);
                o4[j] = fmaf(w0[64 + 16*j],  hv.y, o4[j]);
                o4[j] = fmaf(w0[128 + 16*j], hv.z, o4[j]);
                o4[j] = fmaf(w0[192 + 16*j], hv.w, o4[j]);
            }
        }
    }
    wsync();   // sOut aliases wave's L half (dead after phase B)
    {
        const int w   = threadIdx.x >> 6;     // wave id (0/1)
        const int l   = threadIdx.x & 63;
        float* sOutW  = sm + 2080 + w*1040;   // 256 floats used
        const int pt3 = pt & 3;
        #pragma unroll
        for (int j = 0; j < 4; j++)
            sOutW[4*(k + 16*j) + pt3] = fmaxf(fmaf(m4g[k+16*j], o4[j], m4b[k+16*j]), 0.f);
        wsync();
        const int pbase = blockIdx.x << 3;
        const int b0 = pbase / NN;
        const int n0 = pbase - b0 * NN + 4*w;
        float4 u = *(const float4*)(sOutW + 4*l);
        *(float4*)(outp + (size_t)(b0*64 + l)*NN + n0) = u;
    }
}

extern "C" void kernel_launch(void* const* d_in, const int* in_sizes, int n_in,
                              void* d_out, int out_size, void* d_ws, size_t ws_size,
                              hipStream_t stream) {
    float* outp = (float*)d_out;

    // Deterministic contract check, encoded in fill value (capture-safe).
    float fillv = 1.0f;
    bool ok = true;
    if (n_in != 32) { fillv = 5.0f; ok = false; }
    else if (in_sizes[0] != 1310720 || in_sizes[1] != 245760 ||
             in_sizes[31] != 1310720) { fillv = 7.0f; ok = false; }
    else if (out_size != 5242880) { fillv = 9.0f; ok = false; }
    else if (ws_size < ((size_t)NPTS * 16 + WTOT) * sizeof(float)) { fillv = 11.0f; ok = false; }

    k_fill4<<<1024, 256, 0, stream>>>((float4*)outp, fillv, out_size/4);
    if (!ok) return;

    const float* featp = (const float*)d_in[0];
    const float* xyzp  = (const float*)d_in[1];
    const int*   nidx  = (const int*)d_in[31];

    // feat0 (5.25 MB) in d_out scratch: dead before stage2's final stores.
    float* feat0 = (float*)d_out;
    float* feat1 = (float*)d_ws;                       // NPTS*16 f32
    float* wb    = (float*)d_ws + (size_t)NPTS * 16;   // WTOT f32

    #define W(i) ((const float*)d_in[2 + (i)])
    k_prep<<<8, 256, 0, stream>>>(W(9), W(13), W(10), W(14), W(17), W(20),
                                  W(23), W(26), wb);
    k_feat0<<<NPTS/256, 256, 0, stream>>>(featp, W(0), W(1), W(2), feat0);
    k_stage1<<<NPTS/8, 128, 0, stream>>>(xyzp, nidx, feat0,
        W(3), W(4), W(5), wb, W(11), W(12), feat1);
    k_stage2<<<NPTS/8, 128, 0, stream>>>(featp, xyzp, nidx, feat1,
        W(3), W(4), W(5),          // lm1
        W(6), W(7), W(8),          // lm2
        wb,                        // transposed weights
        W(15), W(16),              // p2m g/b
        W(18), W(19),              // m2 g/b
        W(21), W(22),              // sc g/b
        W(24), W(25),              // m3 g/b
        W(27), W(28),              // m4 g/b
        outp);
    #undef W
}

// Round 11
// 362.060 us; speedup vs baseline: 1.8129x; 1.0046x over previous
//
#include <hip/hip_runtime.h>

#define NN 20480
#define NPTS 81920   // B(4) * N(20480)
#define PS 260       // per-point plane stride (16k x 16ch + 4 pad)
#define MS 36        // mid/act row stride

// transposed-weight offsets inside ws weight region (floats)
#define P1FCT 0
#define P2FCT 1088
#define P1MWT 2176
#define P2MWT 2688
#define M2WT  3712
#define SCWT  5760
#define M3WT  6784
#define M4WT  7040
#define WTOT  15232

__device__ __forceinline__ float redsum16(float v){
    v += __shfl_xor(v, 1); v += __shfl_xor(v, 2);
    v += __shfl_xor(v, 4); v += __shfl_xor(v, 8);
    return v;
}
__device__ __forceinline__ float redmax16(float v){
    v = fmaxf(v, __shfl_xor(v, 1)); v = fmaxf(v, __shfl_xor(v, 2));
    v = fmaxf(v, __shfl_xor(v, 4)); v = fmaxf(v, __shfl_xor(v, 8));
    return v;
}
// Wave-scope LDS producer->consumer fence (all phase dataflow is wave-local).
__device__ __forceinline__ void wsync(){
    __builtin_amdgcn_wave_barrier();
    __threadfence_block();
    __builtin_amdgcn_wave_barrier();
}
__device__ __forceinline__ float frcp(float x){ return __builtin_amdgcn_rcpf(x); }

// Fast atan2: minimax deg-9 atan poly on [0,1] (max err ~1.4e-4 rad; 2% task
// tolerance). atan2(0,0)=0 like numpy.
__device__ __forceinline__ float fatan2(float y, float x){
    float ax = fabsf(x), ay = fabsf(y);
    float mx = fmaxf(ax, ay), mn = fminf(ax, ay);
    float z = mn * frcp(mx);
    z = (mx == 0.f) ? 0.f : z;
    float z2 = z * z;
    float a = fmaf(0.05265332f, z2, -0.11643287f);
    a = fmaf(a, z2, 0.19354346f);
    a = fmaf(a, z2, -0.33262347f);
    a = fmaf(a, z2, 0.99997726f);
    a = a * z;
    a = (ay > ax) ? (1.5707963268f - a) : a;
    a = (x < 0.f) ? (3.1415926536f - a) : a;
    return (y < 0.f) ? -a : a;
}

// Batch<->XCD affinity swizzle (grid = 10240 blocks, XCD = blockIdx%8 assumed):
// XCD pair x>>1 owns batch x>>1 -> per-XCD gather set fits 4MB L2.
__device__ __forceinline__ int swiz(int bid){
    int x = bid & 7, s = bid >> 3;             // s in [0,1280)
    return ((x >> 1) * 2560) + ((x & 1) * 1280) + s;
}

__global__ void k_fill4(float4* out, float val, int n4){
    int i = blockIdx.x * blockDim.x + threadIdx.x;
    int stride = gridDim.x * blockDim.x;
    float4 v = make_float4(val, val, val, val);
    for (; i < n4; i += stride) out[i] = v;
}

// Transpose weight matrices to [c][o] layout so consumers read coalesced.
__global__ void k_prep(
    const float* __restrict__ p1fc, const float* __restrict__ p2fc,
    const float* __restrict__ p1mW, const float* __restrict__ p2mW,
    const float* __restrict__ m2W,  const float* __restrict__ scW,
    const float* __restrict__ m3W,  const float* __restrict__ m4W,
    float* __restrict__ wb)
{
    const float* src = p1fc; float* dst = wb; int No = 32, Nc = 34, tot = 1088;
    switch (blockIdx.x){
        case 0: break;
        case 1: src = p2fc; dst = wb + P2FCT; break;
        case 2: src = p1mW; dst = wb + P1MWT; No = 16; Nc = 32; tot = 512;  break;
        case 3: src = p2mW; dst = wb + P2MWT; No = 32; Nc = 32; tot = 1024; break;
        case 4: src = m2W;  dst = wb + M2WT;  No = 64; Nc = 32; tot = 2048; break;
        case 5: src = scW;  dst = wb + SCWT;  No = 64; Nc = 16; tot = 1024; break;
        case 6: src = m3W;  dst = wb + M3WT;  No = 64; Nc = 4;  tot = 256;  break;
        case 7: src = m4W;  dst = wb + M4WT;  No = 64; Nc = 128;tot = 8192; break;
        default: return;
    }
    for (int e = threadIdx.x; e < tot; e += 256){
        int c = e / No, o = e - c * No;
        dst[e] = src[o * Nc + c];
    }
}

// f_pc = relu(g * (m1_W @ feature) + b), stored point-major (B,N,16) f32
__global__ __launch_bounds__(256) void k_feat0(
    const float* __restrict__ featp,
    const float* __restrict__ m1W,
    const float* __restrict__ m1g,
    const float* __restrict__ m1b,
    float* __restrict__ feat0)
{
    int p = blockIdx.x * 256 + threadIdx.x;
    if (p >= NPTS) return;
    int b = p / NN;
    int n = p - b * NN;
    float x[16];
    #pragma unroll
    for (int c = 0; c < 16; c++) x[c] = featp[(b*16 + c)*NN + n];
    float* dst = feat0 + (size_t)p * 16;
    for (int o = 0; o < 16; o++){
        float acc = 0.f;
        #pragma unroll
        for (int c = 0; c < 16; c++) acc = fmaf(m1W[o*16 + c], x[c], acc);
        dst[o] = fmaxf(fmaf(m1g[o], acc, m1b[o]), 0.f);
    }
}

// Phase B: wave = 2 points x 32 channels per pass (2 passes = wave's 4 pts).
// Weights COALESCED from transposed fcT[c][o].
__device__ __forceinline__ void phaseB(
    const float* __restrict__ fcT, float* sm,
    int gOff, int dOff, int midOff, int tid)
{
    const int l  = tid & 63;
    const int o  = l & 31;
    const int h  = l >> 5;
    const int wv = tid >> 6;

    float w[34];
    #pragma unroll
    for (int c = 0; c < 34; c++) w[c] = fcT[c*32 + o];   // coalesced

    #pragma unroll
    for (int pp = 0; pp < 2; pp++){
        const int ptB = (wv << 2) + (pp << 1) + h;
        const float* fPB = sm + ptB*PS;
        const float* lPB = sm + 2080 + ptB*PS;
        const float* fsvP = (o < 16) ? (fPB + o) : (lPB + (o - 16));

        float lg[16];
        #pragma unroll
        for (int kk = 0; kk < 16; kk++){
            float g = sm[gOff + ptB*16 + kk];
            float d = sm[dOff + ptB*16 + kk];
            float a = fmaf(w[1], d, w[0]*g);
            const float4* fr = (const float4*)(fPB + kk*16);
            const float4* lr = (const float4*)(lPB + kk*16);
            #pragma unroll
            for (int v = 0; v < 4; v++){
                float4 F = fr[v]; float4 L = lr[v];
                a = fmaf(w[2+4*v],  F.x, a); a = fmaf(w[3+4*v],  F.y, a);
                a = fmaf(w[4+4*v],  F.z, a); a = fmaf(w[5+4*v],  F.w, a);
                a = fmaf(w[18+4*v], L.x, a); a = fmaf(w[19+4*v], L.y, a);
                a = fmaf(w[20+4*v], L.z, a); a = fmaf(w[21+4*v], L.w, a);
            }
            lg[kk] = a;
        }
        float m0 = fmaxf(fmaxf(fmaxf(lg[0],lg[1]), fmaxf(lg[2],lg[3])),
                         fmaxf(fmaxf(lg[4],lg[5]), fmaxf(lg[6],lg[7])));
        float m1 = fmaxf(fmaxf(fmaxf(lg[8],lg[9]), fmaxf(lg[10],lg[11])),
                         fmaxf(fmaxf(lg[12],lg[13]), fmaxf(lg[14],lg[15])));
        float mx = fmaxf(m0, m1);
        float s = 0.f, num = 0.f;
        #pragma unroll
        for (int kk = 0; kk < 16; kk++){
            float e = __expf(lg[kk] - mx);
            s += e;
            num = fmaf(e, fsvP[kk*16], num);
        }
        sm[midOff + ptB*MS + o] = num * frcp(s);
    }
}

// ---------------- Stage 1 ----------------
// LDS floats: F=0(2080) L=2080(2080) G=4160(128) D=4288(128) MID=4416(288)
__global__ __launch_bounds__(128, 2) void k_stage1(
    const float* __restrict__ xyzp,
    const int* __restrict__ nidx,
    const float* __restrict__ feat0,
    const float* __restrict__ lm1W,
    const float* __restrict__ lm1g,
    const float* __restrict__ lm1b,
    const float* __restrict__ wb,
    const float* __restrict__ p1mg,
    const float* __restrict__ p1mb,
    float* __restrict__ feat1)
{
    __shared__ float sm[4704];
    const int k  = threadIdx.x & 15;
    const int pt = threadIdx.x >> 4;
    const int p  = (swiz(blockIdx.x) << 3) + pt;
    const int b  = p / NN;

    // ---- Phase A ----
    {
        const int ii = nidx[(p << 4) + k];
        const int q  = b * NN + ii;
        const float4* an = (const float4*)(feat0 + (size_t)q * 16);
        const float4* as = (const float4*)(feat0 + (size_t)p * 16);
        const float sx = xyzp[p*3 + 0];
        const float sy = xyzp[p*3 + 1];
        const float sz = xyzp[p*3 + 2];
        const float nx = xyzp[q*3 + 0];
        const float ny = xyzp[q*3 + 1];
        const float nz = xyzp[q*3 + 2];

        float* fRow = sm + pt*PS + k*16;
        float sd = 0.f;
        #pragma unroll
        for (int v = 0; v < 4; v++){
            float4 A = an[v]; float4 S = as[v];
            ((float4*)fRow)[v] = A;
            sd += fabsf(S.x-A.x) + fabsf(S.y-A.y) + fabsf(S.z-A.z) + fabsf(S.w-A.w);
        }
        sm[4288 + pt*16 + k] = 2.f * __expf(-sd * 0.0625f);   // LAMDA*f_dis

        float rx = sx - nx, ry = sy - ny, rz = sz - nz;
        float r2 = rx*rx + ry*ry;
        float rdis = sqrtf(r2 + rz*rz);
        float ralpha = fatan2(ry, rx);
        float rbeta  = fatan2(rz, sqrtf(r2));
        sm[4160 + pt*16 + k] = __expf(-rdis);                 // g_dis

        float mx = redsum16(nx) * 0.0625f;
        float my = redsum16(ny) * 0.0625f;
        float mz = redsum16(nz) * 0.0625f;
        float dx = sx - mx, dy = sy - my, dz = sz - mz;
        float dalpha = fatan2(dy, dx);
        float dbeta  = fatan2(dz, sqrtf(dx*dx + dy*dy));

        const float r0 = ralpha - dalpha, r1 = rbeta - dbeta;
        float* lRow = sm + 2080 + pt*PS + k*16;
        for (int o = 0; o < 16; o++){        // uniform-index: s_load weights
            const float* wr = lm1W + o*9;
            float acc =        wr[0]*r0;
            acc = fmaf(wr[1], r1,   acc); acc = fmaf(wr[2], rdis, acc);
            acc = fmaf(wr[3], sx,   acc); acc = fmaf(wr[4], sy,   acc);
            acc = fmaf(wr[5], sz,   acc); acc = fmaf(wr[6], nx,   acc);
            acc = fmaf(wr[7], ny,   acc); acc = fmaf(wr[8], nz,   acc);
            lRow[o] = fmaxf(fmaf(lm1g[o], acc, lm1b[o]), 0.f);
        }
    }
    wsync();

    phaseB(wb + P1FCT, sm, 4160, 4288, 4416, threadIdx.x);
    wsync();

    // ---- Phase C : p1m row k (coalesced transposed weights) ----
    {
        float mid[32];
        const float4* mp = (const float4*)(sm + 4416 + pt*MS);
        #pragma unroll
        for (int i = 0; i < 8; i++){
            float4 t = mp[i];
            mid[4*i]=t.x; mid[4*i+1]=t.y; mid[4*i+2]=t.z; mid[4*i+3]=t.w;
        }
        const float* wt = wb + P1MWT;
        float acc = 0.f;
        #pragma unroll
        for (int c = 0; c < 32; c++) acc = fmaf(wt[c*16 + k], mid[c], acc);
        feat1[(size_t)(p << 4) + k] = fmaxf(fmaf(p1mg[k], acc, p1mb[k]), 0.f);
    }
}

// ---------------- Stage 2 ----------------
// LDS floats: F=0(2080) L=2080(2080) G=4160(128) D=4288(128) LGR=4416(8)
//             MID=4424(288) ACT=4712(288)  -> 20000 B = 8 blocks/CU
__global__ __launch_bounds__(128, 2) void k_stage2(
    const float* __restrict__ featp,
    const float* __restrict__ xyzp,
    const int* __restrict__ nidx,
    const float* __restrict__ feat1,
    const float* __restrict__ lm1W,
    const float* __restrict__ lm1g,
    const float* __restrict__ lm1b,
    const float* __restrict__ lm2W,
    const float* __restrict__ lm2g,
    const float* __restrict__ lm2b,
    const float* __restrict__ wb,
    const float* __restrict__ p2mg,
    const float* __restrict__ p2mb,
    const float* __restrict__ m2g,
    const float* __restrict__ m2b,
    const float* __restrict__ scg,
    const float* __restrict__ scb,
    const float* __restrict__ m3g,
    const float* __restrict__ m3b,
    const float* __restrict__ m4g,
    const float* __restrict__ m4b,
    float* __restrict__ outp)
{
    __shared__ float sm[5000];
    const int k    = threadIdx.x & 15;
    const int pt   = threadIdx.x >> 4;
    const int pblk = swiz(blockIdx.x);
    const int p    = (pblk << 3) + pt;
    const int b    = p / NN;
    const int n    = p - b * NN;

    // ---- Phase A ----
    {
        const int ii = nidx[(p << 4) + k];
        const int q  = b * NN + ii;
        const float4* an = (const float4*)(feat1 + (size_t)q * 16);
        const float4* as = (const float4*)(feat1 + (size_t)p * 16);
        const float sx = xyzp[p*3 + 0];
        const float sy = xyzp[p*3 + 1];
        const float sz = xyzp[p*3 + 2];
        const float nx = xyzp[q*3 + 0];
        const float ny = xyzp[q*3 + 1];
        const float nz = xyzp[q*3 + 2];

        float* fRow = sm + pt*PS + k*16;
        float sd = 0.f;
        #pragma unroll
        for (int v = 0; v < 4; v++){
            float4 A = an[v]; float4 S = as[v];
            ((float4*)fRow)[v] = A;
            sd += fabsf(S.x-A.x) + fabsf(S.y-A.y) + fabsf(S.z-A.z) + fabsf(S.w-A.w);
        }
        sm[4288 + pt*16 + k] = 2.f * __expf(-sd * 0.0625f);

        float rx = sx - nx, ry = sy - ny, rz = sz - nz;
        float r2 = rx*rx + ry*ry;
        float rdis = sqrtf(r2 + rz*rz);
        float ralpha = fatan2(ry, rx);
        float rbeta  = fatan2(rz, sqrtf(r2));
        sm[4160 + pt*16 + k] = __expf(-rdis);

        float mx = redsum16(nx) * 0.0625f;
        float my = redsum16(ny) * 0.0625f;
        float mz = redsum16(nz) * 0.0625f;
        float dx = sx - mx, dy = sy - my, dz = sz - mz;
        float dalpha = fatan2(dy, dx);
        float dbeta  = fatan2(dz, sqrtf(dx*dx + dy*dy));

        float mxd = redmax16(rdis);
        float nr  = sqrtf(sx*sx + sy*sy + sz*sz);
        if (k == 0) sm[4416 + pt] = (mxd*mxd*mxd) * frcp(nr*nr*nr);  // lg_ratio

        const float r0 = ralpha - dalpha, r1 = rbeta - dbeta;
        float rep[9] = { r0, r1, rdis, sx, sy, sz, nx, ny, nz };
        float lrep[16];
        #pragma unroll
        for (int o = 0; o < 16; o++){
            float acc = 0.f;
            #pragma unroll
            for (int c = 0; c < 9; c++) acc = fmaf(lm1W[o*9 + c], rep[c], acc);
            lrep[o] = fmaxf(fmaf(lm1g[o], acc, lm1b[o]), 0.f);
        }
        float* lRow = sm + 2080 + pt*PS + k*16;
        for (int o = 0; o < 16; o++){
            float acc = 0.f;
            #pragma unroll
            for (int c = 0; c < 16; c++) acc = fmaf(lm2W[o*16 + c], lrep[c], acc);
            lRow[o] = fmaxf(fmaf(lm2g[o], acc, lm2b[o]), 0.f);   // lrep2
        }
    }
    wsync();

    phaseB(wb + P2FCT, sm, 4160, 4288, 4424, threadIdx.x);
    wsync();

    // ---- Phase C1 : p2m (relu) -> ACT ----
    {
        float mid[32];
        const float4* mp = (const float4*)(sm + 4424 + pt*MS);
        #pragma unroll
        for (int i = 0; i < 8; i++){
            float4 t = mp[i];
            mid[4*i]=t.x; mid[4*i+1]=t.y; mid[4*i+2]=t.z; mid[4*i+3]=t.w;
        }
        const float* wt = wb + P2MWT;
        float actA = 0.f, actB = 0.f;
        #pragma unroll
        for (int c = 0; c < 32; c++){
            actA = fmaf(wt[c*32 + k],      mid[c], actA);
            actB = fmaf(wt[c*32 + k + 16], mid[c], actB);
        }
        sm[4712 + pt*MS + k]      = fmaxf(fmaf(p2mg[k],    actA, p2mb[k]),    0.f);
        sm[4712 + pt*MS + k + 16] = fmaxf(fmaf(p2mg[k+16], actB, p2mb[k+16]), 0.f);
    }
    wsync();

    // ---- Phase C2 : m2 + sc + m3 -> sH ----
    {
        float act[32];
        const float4* ap = (const float4*)(sm + 4712 + pt*MS);
        #pragma unroll
        for (int i = 0; i < 8; i++){
            float4 t = ap[i];
            act[4*i]=t.x; act[4*i+1]=t.y; act[4*i+2]=t.z; act[4*i+3]=t.w;
        }
        const float* wt2 = wb + M2WT;
        float hA[4] = {0.f, 0.f, 0.f, 0.f};
        #pragma unroll
        for (int c = 0; c < 32; c++){
            float a = act[c];
            #pragma unroll
            for (int j = 0; j < 4; j++)
                hA[j] = fmaf(wt2[c*64 + k + 16*j], a, hA[j]);
        }
        const float* wts = wb + SCWT;
        float sA4[4] = {0.f, 0.f, 0.f, 0.f};
        for (int i = 0; i < 4; i++){
            float x0 = featp[(b*16 + 4*i + 0)*NN + n];
            float x1 = featp[(b*16 + 4*i + 1)*NN + n];
            float x2 = featp[(b*16 + 4*i + 2)*NN + n];
            float x3 = featp[(b*16 + 4*i + 3)*NN + n];
            #pragma unroll
            for (int j = 0; j < 4; j++){
                sA4[j] = fmaf(wts[(4*i+0)*64 + k + 16*j], x0, sA4[j]);
                sA4[j] = fmaf(wts[(4*i+1)*64 + k + 16*j], x1, sA4[j]);
                sA4[j] = fmaf(wts[(4*i+2)*64 + k + 16*j], x2, sA4[j]);
                sA4[j] = fmaf(wts[(4*i+3)*64 + k + 16*j], x3, sA4[j]);
            }
        }
        const float sx = xyzp[p*3 + 0];
        const float sy = xyzp[p*3 + 1];
        const float sz = xyzp[p*3 + 2];
        const float lgr = sm[4416 + pt];
        const float v3[4] = { sx, sy, sz, lgr };
        const float* wt3 = wb + M3WT;
        float* sH = sm + pt*PS;     // F slice of this pt (dead after phase B)
        #pragma unroll
        for (int j = 0; j < 4; j++){
            int oo = k + 16*j;
            float scv = fmaf(scg[oo], sA4[j], scb[oo]);
            float m2v = fmaf(m2g[oo], hA[j],  m2b[oo]);
            float acc = 0.f;
            #pragma unroll
            for (int c = 0; c < 4; c++) acc = fmaf(wt3[c*64 + oo], v3[c], acc);
            sH[oo]      = m2v + scv;
            sH[64 + oo] = fmaf(m3g[oo], acc, m3b[oo]);
        }
    }
    wsync();

    // ---- Phase C3 : m4 (relu), coalesced transposed weights ----
    float o4[4] = {0.f, 0.f, 0.f, 0.f};
    {
        const float* hRow = sm + pt*PS;
        const float* wt4 = wb + M4WT;
        for (int cb = 0; cb < 32; cb++){
            const float4 hv = *(const float4*)(hRow + cb*4);
            const float* w0 = wt4 + (cb*4)*64 + k;
            #pragma unroll
            for (int j = 0; j < 4; j++){
                o4[j] = fmaf(w0[16*j],       hv.x, o4[j]);
                o4[j] = fmaf(w0[64 + 16*j],  hv.y, o4[j]);
                o4[j] = fmaf(w0[128 + 16*j], hv.z, o4[j]);
                o4[j] = fmaf(w0[192 + 16*j], hv.w, o4[j]);
            }
        }
    }
    wsync();   // sOut aliases wave's L half (dead after phase B)
    {
        const int w   = threadIdx.x >> 6;     // wave id (0/1)
        const int l   = threadIdx.x & 63;
        float* sOutW  = sm + 2080 + w*1040;   // 256 floats used
        const int pt3 = pt & 3;
        #pragma unroll
        for (int j = 0; j < 4; j++)
            sOutW[4*(k + 16*j) + pt3] = fmaxf(fmaf(m4g[k+16*j], o4[j], m4b[k+16*j]), 0.f);
        wsync();
        const int pbase = pblk << 3;
        const int b0 = pbase / NN;
        const int n0 = pbase - b0 * NN + 4*w;
        float4 u = *(const float4*)(sOutW + 4*l);
        *(float4*)(outp + (size_t)(b0*64 + l)*NN + n0) = u;
    }
}

extern "C" void kernel_launch(void* const* d_in, const int* in_sizes, int n_in,
                              void* d_out, int out_size, void* d_ws, size_t ws_size,
                              hipStream_t stream) {
    float* outp = (float*)d_out;

    // Deterministic contract check, encoded in fill value (capture-safe).
    float fillv = 1.0f;
    bool ok = true;
    if (n_in != 32) { fillv = 5.0f; ok = false; }
    else if (in_sizes[0] != 1310720 || in_sizes[1] != 245760 ||
             in_sizes[31] != 1310720) { fillv = 7.0f; ok = false; }
    else if (out_size != 5242880) { fillv = 9.0f; ok = false; }
    else if (ws_size < ((size_t)NPTS * 16 + WTOT) * sizeof(float)) { fillv = 11.0f; ok = false; }

    k_fill4<<<1024, 256, 0, stream>>>((float4*)outp, fillv, out_size/4);
    if (!ok) return;

    const float* featp = (const float*)d_in[0];
    const float* xyzp  = (const float*)d_in[1];
    const int*   nidx  = (const int*)d_in[31];

    // feat0 (5.25 MB) in d_out scratch: dead before stage2's final stores.
    float* feat0 = (float*)d_out;
    float* feat1 = (float*)d_ws;                       // NPTS*16 f32
    float* wb    = (float*)d_ws + (size_t)NPTS * 16;   // WTOT f32

    #define W(i) ((const float*)d_in[2 + (i)])
    k_prep<<<8, 256, 0, stream>>>(W(9), W(13), W(10), W(14), W(17), W(20),
                                  W(23), W(26), wb);
    k_feat0<<<NPTS/256, 256, 0, stream>>>(featp, W(0), W(1), W(2), feat0);
    k_stage1<<<NPTS/8, 128, 0, stream>>>(xyzp, nidx, feat0,
        W(3), W(4), W(5), wb, W(11), W(12), feat1);
    k_stage2<<<NPTS/8, 128, 0, stream>>>(featp, xyzp, nidx, feat1,
        W(3), W(4), W(5),          // lm1
        W(6), W(7), W(8),          // lm2
        wb,                        // transposed weights
        W(15), W(16),              // p2m g/b
        W(18), W(19),              // m2 g/b
        W(21), W(22),              // sc g/b
        W(24), W(25),              // m3 g/b
        W(27), W(28),              // m4 g/b
        outp);
    #undef W
}